// Round 1
// 182.160 us; speedup vs baseline: 1.0248x; 1.0248x over previous
//
#include <hip/hip_runtime.h>

#define B_    4
#define C_    256
#define O_    128
#define N_    4096
#define THW   256     // thph row width (theta | phi)
#define TILES 64      // N/64 key tiles (attn uses TK=64)

typedef __attribute__((ext_vector_type(8))) _Float16 f16x8;
typedef __attribute__((ext_vector_type(4))) float    f32x4;

struct __align__(8) us4 { unsigned short x, y, z, w; };

__device__ __forceinline__ float bf2f(unsigned short u) {
    unsigned v = ((unsigned)u) << 16;
    union { unsigned u; float f; } c; c.u = v; return c.f;
}
__device__ __forceinline__ unsigned short f2bf(float f) {
    union { float f; unsigned u; } c; c.f = f;
    unsigned r = c.u + 0x7fffu + ((c.u >> 16) & 1u);
    return (unsigned short)(r >> 16);
}
__device__ __forceinline__ unsigned short f2h(float f) {
    _Float16 h = (_Float16)f;
    union { _Float16 h; unsigned short s; } c; c.h = h; return c.s;
}
__device__ __forceinline__ float h2f(unsigned short s) {
    union { unsigned short s; _Float16 h; } c; c.s = s; return (float)c.h;
}

__device__ __forceinline__ void load4f(const void* base, size_t idx, int isf32, float o[4]) {
    if (isf32) {
        float4 v = *(const float4*)((const float*)base + idx);
        o[0] = v.x; o[1] = v.y; o[2] = v.z; o[3] = v.w;
    } else {
        us4 v = *(const us4*)((const unsigned short*)base + idx);
        o[0] = bf2f(v.x); o[1] = bf2f(v.y); o[2] = bf2f(v.z); o[3] = bf2f(v.w);
    }
}
__device__ __forceinline__ float load1f(const void* base, size_t idx, int isf32) {
    return isf32 ? ((const float*)base)[idx] : bf2f(((const unsigned short*)base)[idx]);
}

// ---------------------------------------------------------------------------
// Kernel 0: input dtype detector (fp32 confirmed live; kept for robustness).
// ---------------------------------------------------------------------------
__global__ __launch_bounds__(256) void detect_kernel(
    const unsigned short* __restrict__ xu, int* __restrict__ flag)
{
    __shared__ int cnt;
    if (threadIdx.x == 0) cnt = 0;
    __syncthreads();
    int local = 0;
    for (int i = threadIdx.x; i < 4096; i += 256) {
        unsigned short u = xu[2 * i];
        int e = (u >> 7) & 0xFF;
        if (e == 0xFF || e >= 0x90 || (e > 0 && e <= 0x60)) local++;
    }
    atomicAdd(&cnt, local);
    __syncthreads();
    if (threadIdx.x == 0) *flag = (cnt > 1024) ? 1 : 0;
}

// ---------------------------------------------------------------------------
// Kernel 1: conv1x1 x3 -> thph [B][N][256] (theta|phi), gT [B][128][N].
// (unchanged — swizzled As transpose, conflict-free)
// ---------------------------------------------------------------------------
__global__ __launch_bounds__(256) void qkv_kernel(
    const void* __restrict__ x,
    const void* __restrict__ wt, const void* __restrict__ wp,
    const void* __restrict__ wg,
    const void* __restrict__ bt, const void* __restrict__ bp,
    const void* __restrict__ bg,
    const int*  __restrict__ flag,
    unsigned short* __restrict__ thph,
    unsigned short* __restrict__ gT)
{
    const int isf32 = *flag;
    const int jsel = blockIdx.y;
    const void* w  = jsel == 0 ? wt : (jsel == 1 ? wp : wg);
    const void* bi = jsel == 0 ? bt : (jsel == 1 ? bp : bg);
    const int b  = blockIdx.z;
    const int n0 = blockIdx.x * 64;
    const int tid  = threadIdx.x;
    const int wv   = tid >> 6, lane = tid & 63;
    const int quad = lane >> 4, l16 = lane & 15;

    __shared__ alignas(16) unsigned short smem[64 * 72 + 128 * 72];
    unsigned short (*As)[72] = (unsigned short(*)[72])smem;
    unsigned short (*Bs)[72] = (unsigned short(*)[72])(smem + 64 * 72);

    f32x4 acc[8];
    for (int i = 0; i < 8; i++) acc[i] = (f32x4)0.f;

    for (int kc = 0; kc < C_; kc += 64) {
        __syncthreads();
        for (int it = 0; it < 4; it++) {
            int l = it * 256 + tid;
            int c = l >> 4;
            int ng = l & 15;
            float v[4];
            load4f(x, (size_t)(b * C_ + kc + c) * N_ + n0 + ng * 4, isf32, v);
            int g = c >> 3, cl = c & 7;
            int swz = ((g ^ (ng & 7)) << 3) + cl;
            As[ng * 4 + 0][swz] = f2h(v[0]);
            As[ng * 4 + 1][swz] = f2h(v[1]);
            As[ng * 4 + 2][swz] = f2h(v[2]);
            As[ng * 4 + 3][swz] = f2h(v[3]);
        }
        for (int it = 0; it < 8; it++) {
            int l = it * 256 + tid;
            int j = l >> 4;
            int cg = l & 15;
            float v[4];
            load4f(w, (size_t)j * C_ + kc + cg * 4, isf32, v);
            Bs[j][cg * 4 + 0] = f2h(v[0]);
            Bs[j][cg * 4 + 1] = f2h(v[1]);
            Bs[j][cg * 4 + 2] = f2h(v[2]);
            Bs[j][cg * 4 + 3] = f2h(v[3]);
        }
        __syncthreads();
        for (int s = 0; s < 2; s++) {
            int row = wv * 16 + l16;
            int g2 = ((s * 4 + quad) ^ ((row >> 2) & 7)) << 3;
            f16x8 a = *(const f16x8*)&As[row][g2];
            for (int jt = 0; jt < 8; jt++) {
                f16x8 bb = *(const f16x8*)&Bs[jt * 16 + l16][s * 32 + quad * 8];
                acc[jt] = __builtin_amdgcn_mfma_f32_16x16x32_f16(a, bb, acc[jt], 0, 0, 0);
            }
        }
    }

    if (jsel < 2) {
        for (int jt = 0; jt < 8; jt++) {
            int j = jt * 16 + l16;
            float bias = load1f(bi, j, isf32);
            for (int r = 0; r < 4; r++) {
                int n = n0 + wv * 16 + quad * 4 + r;
                thph[(size_t)(b * N_ + n) * THW + jsel * O_ + j] = f2h(acc[jt][r] + bias);
            }
        }
    } else {
        unsigned short (*T)[68] = (unsigned short(*)[68])smem;
        __syncthreads();
        for (int jt = 0; jt < 8; jt++) {
            int j = jt * 16 + l16;
            float bias = load1f(bi, j, isf32);
            for (int r = 0; r < 4; r++) {
                int nl = wv * 16 + quad * 4 + r;
                T[j][nl] = f2h(acc[jt][r] + bias);
            }
        }
        __syncthreads();
        for (int it = 0; it < 8; it++) {
            int l = it * 256 + tid;
            int j = l >> 4;
            int ng = l & 15;
            *(us4*)(gT + ((size_t)(b * O_ + j)) * N_ + n0 + ng * 4) = *(const us4*)&T[j][ng * 4];
        }
    }
}

// ---------------------------------------------------------------------------
// Kernel 2: flash-attention partial. 256 threads = 4 waves, Q-tile 128,
// 32 queries (2 groups of 16) per wave -> every K/G LDS fragment read feeds
// TWO MFMAs (reads/MFMA 1.06 -> 0.56; LDS traffic -40%).
// PV computed transposed (O^T = G P^T): softmax alpha is the lane's OWN
// value (no ds_bpermute broadcast), epilogue packs 4 consecutive o -> us4.
// grid (N/128, S, B); S=4 -> 512 blocks = 2 blocks/CU (LDS 2x54KB <= 160,
// VGPR ~190 capped 256 via launch_bounds(256,2) -> 8 waves/CU).
// ---------------------------------------------------------------------------
__global__ __launch_bounds__(256, 2) void attn_partial(
    const unsigned short* __restrict__ thph,  // fp16 [B][N][256]
    const unsigned short* __restrict__ gT,    // fp16 [B][128][N]
    unsigned short* __restrict__ partO,       // fp16 [S][B][N][128]
    float* __restrict__ pm,                   // [S][B][N]
    float* __restrict__ pl,                   // [S][B][N]
    int S)
{
    const int b    = blockIdx.z;
    const int s_id = blockIdx.y;
    const int n0   = blockIdx.x * 128;
    const int tid  = threadIdx.x;
    const int wv   = tid >> 6, lane = tid & 63;
    const int quad = lane >> 4, l16 = lane & 15;

    const int t0 = (TILES * s_id) / S;
    const int t1 = (TILES * (s_id + 1)) / S;

    __shared__ alignas(16) unsigned short Ks[64][136];   // [key][o]
    __shared__ alignas(16) unsigned short Gs[128][72];   // [o][key]
    __shared__ alignas(16) unsigned short Ps[4][32][72]; // per-wave P [q][key]

    const int wq0 = n0 + wv * 32;   // this wave's 32 queries

    // Q fragments (B operand of K Q^T): col = query (l16 within group)
    f16x8 qf[2][4];
    #pragma unroll
    for (int qg = 0; qg < 2; qg++) {
        const unsigned short* qp = thph + (size_t)(b * N_ + wq0 + qg * 16 + l16) * THW;
        #pragma unroll
        for (int s = 0; s < 4; s++)
            qf[qg][s] = *(const f16x8*)(qp + s * 32 + quad * 8);
    }

    // O^T accumulator: oacc[qg][jt] rows o = jt*16+quad*4+r, col q = l16
    f32x4 oacc[2][8];
    #pragma unroll
    for (int qg = 0; qg < 2; qg++)
        #pragma unroll
        for (int i = 0; i < 8; i++) oacc[qg][i] = (f32x4)0.f;
    float mst[2] = { -INFINITY, -INFINITY };
    float lst[2] = { 0.f, 0.f };

    // staging: thread-invariant addressing, 16B granules
    const int krow = tid >> 4, kog = tid & 15;   // K: 64 rows x 16 chunks
    const int grow = tid >> 3, gng = tid & 7;    // G: 128 rows x 8 chunks
    const unsigned short* kb_g = thph + (size_t)(b * N_ + krow) * THW + O_ + kog * 8;
    const unsigned short* gb_g = gT + ((size_t)(b * O_ + grow)) * N_ + gng * 8;

    f16x8 kreg[4], greg[4];
    auto prefetch = [&](int mt) {
        int m0 = mt * 64;
        #pragma unroll
        for (int it = 0; it < 4; it++)
            kreg[it] = *(const f16x8*)(kb_g + (size_t)(m0 + it * 16) * THW);
        #pragma unroll
        for (int it = 0; it < 4; it++)
            greg[it] = *(const f16x8*)(gb_g + m0 + (size_t)it * 32 * N_);
    };
    prefetch(t0);

    for (int mt = t0; mt < t1; mt++) {
        __syncthreads();   // prior tile's LDS reads complete
        #pragma unroll
        for (int it = 0; it < 4; it++)
            *(f16x8*)&Ks[krow + it * 16][kog * 8] = kreg[it];
        #pragma unroll
        for (int it = 0; it < 4; it++)
            *(f16x8*)&Gs[grow + it * 32][gng * 8] = greg[it];
        __syncthreads();   // staging visible
        if (mt + 1 < t1) prefetch(mt + 1);   // in flight across compute

        // S^T = K Q^T : D[row=key-sub(quad*4+r)][col=q(l16)], per q-group.
        // Each Ks read feeds BOTH query groups.
        f32x4 sacc[2][4];
        #pragma unroll
        for (int qg = 0; qg < 2; qg++)
            #pragma unroll
            for (int kt = 0; kt < 4; kt++) sacc[qg][kt] = (f32x4)0.f;
        #pragma unroll
        for (int s = 0; s < 4; s++) {
            #pragma unroll
            for (int kt = 0; kt < 4; kt++) {
                f16x8 kb = *(const f16x8*)&Ks[kt * 16 + l16][s * 32 + quad * 8];
                sacc[0][kt] = __builtin_amdgcn_mfma_f32_16x16x32_f16(kb, qf[0][s], sacc[0][kt], 0, 0, 0);
                sacc[1][kt] = __builtin_amdgcn_mfma_f32_16x16x32_f16(kb, qf[1][s], sacc[1][kt], 0, 0, 0);
            }
        }

        // online softmax per query group: in-lane 16 keys + 2 shfl hops
        #pragma unroll
        for (int qg = 0; qg < 2; qg++) {
            float rm = fmaxf(
                fmaxf(fmaxf(fmaxf(sacc[qg][0][0], sacc[qg][0][1]), fmaxf(sacc[qg][0][2], sacc[qg][0][3])),
                      fmaxf(fmaxf(sacc[qg][1][0], sacc[qg][1][1]), fmaxf(sacc[qg][1][2], sacc[qg][1][3]))),
                fmaxf(fmaxf(fmaxf(sacc[qg][2][0], sacc[qg][2][1]), fmaxf(sacc[qg][2][2], sacc[qg][2][3])),
                      fmaxf(fmaxf(sacc[qg][3][0], sacc[qg][3][1]), fmaxf(sacc[qg][3][2], sacc[qg][3][3]))));
            rm = fmaxf(rm, __shfl_xor(rm, 16));
            rm = fmaxf(rm, __shfl_xor(rm, 32));

            float mnew  = fmaxf(mst[qg], rm);
            float alpha = __expf(mst[qg] - mnew);
            mst[qg] = mnew;

            float rs = 0.f;
            unsigned short* prow = &Ps[wv][qg * 16 + l16][quad * 4];
            #pragma unroll
            for (int kt = 0; kt < 4; kt++) {
                float p0 = __expf(sacc[qg][kt][0] - mnew);
                float p1 = __expf(sacc[qg][kt][1] - mnew);
                float p2 = __expf(sacc[qg][kt][2] - mnew);
                float p3 = __expf(sacc[qg][kt][3] - mnew);
                rs += (p0 + p1) + (p2 + p3);
                us4 pk;
                pk.x = f2h(p0); pk.y = f2h(p1); pk.z = f2h(p2); pk.w = f2h(p3);
                *(us4*)(prow + kt * 16) = pk;   // [q][key] packed 8B
            }
            rs += __shfl_xor(rs, 16);
            rs += __shfl_xor(rs, 32);
            lst[qg] = lst[qg] * alpha + rs;

            // O^T: col = query = own lane's l16 -> own-lane alpha, no shfl
            #pragma unroll
            for (int jt = 0; jt < 8; jt++) oacc[qg][jt] *= alpha;
        }

        // O^T += G P^T  (Ps per-wave: no barrier; lgkmcnt handles order).
        // Each Gs read feeds BOTH query groups.
        #pragma unroll
        for (int s = 0; s < 2; s++) {
            f16x8 pb0 = *(const f16x8*)&Ps[wv][l16][s * 32 + quad * 8];
            f16x8 pb1 = *(const f16x8*)&Ps[wv][16 + l16][s * 32 + quad * 8];
            #pragma unroll
            for (int jt = 0; jt < 8; jt++) {
                f16x8 ga = *(const f16x8*)&Gs[jt * 16 + l16][s * 32 + quad * 8];
                oacc[0][jt] = __builtin_amdgcn_mfma_f32_16x16x32_f16(ga, pb0, oacc[0][jt], 0, 0, 0);
                oacc[1][jt] = __builtin_amdgcn_mfma_f32_16x16x32_f16(ga, pb1, oacc[1][jt], 0, 0, 0);
            }
        }
    }

    // epilogue: lane holds o = jt*16+quad*4+r for query n = wq0+qg*16+l16
    #pragma unroll
    for (int qg = 0; qg < 2; qg++) {
        int n = wq0 + qg * 16 + l16;
        size_t rowb = ((size_t)(s_id * B_ + b) * N_ + n) * O_;
        #pragma unroll
        for (int jt = 0; jt < 8; jt++) {
            us4 v;
            v.x = f2h(oacc[qg][jt][0]);
            v.y = f2h(oacc[qg][jt][1]);
            v.z = f2h(oacc[qg][jt][2]);
            v.w = f2h(oacc[qg][jt][3]);
            *(us4*)(partO + rowb + jt * 16 + quad * 4) = v;
        }
        if (quad == 0) {
            pm[(size_t)(s_id * B_ + b) * N_ + n] = mst[qg];
            pl[(size_t)(s_id * B_ + b) * N_ + n] = lst[qg];
        }
    }
}

// ---------------------------------------------------------------------------
// Kernel 2b: merge split-K partials -> y[b][n][o] (normalized fp16).
// ---------------------------------------------------------------------------
__global__ __launch_bounds__(256) void merge_kernel(
    const unsigned short* __restrict__ partO,
    const float* __restrict__ pm, const float* __restrict__ pl,
    unsigned short* __restrict__ y,
    int S)
{
    int idx = blockIdx.x * 256 + threadIdx.x;
    int bn  = idx >> 5;
    int og  = idx & 31;
    const int BN = B_ * N_;

    float M = -INFINITY;
    for (int s = 0; s < S; s++) M = fmaxf(M, pm[(size_t)s * BN + bn]);
    float w[4];
    float L = 0.f;
    for (int s = 0; s < S; s++) {
        w[s] = __expf(pm[(size_t)s * BN + bn] - M);
        L += w[s] * pl[(size_t)s * BN + bn];
    }
    float inv = 1.0f / L;

    float a0 = 0.f, a1 = 0.f, a2 = 0.f, a3 = 0.f;
    for (int s = 0; s < S; s++) {
        us4 v = *(const us4*)(partO + ((size_t)s * BN + bn) * O_ + og * 4);
        a0 += h2f(v.x) * w[s];
        a1 += h2f(v.y) * w[s];
        a2 += h2f(v.z) * w[s];
        a3 += h2f(v.w) * w[s];
    }
    us4 r;
    r.x = f2h(a0 * inv); r.y = f2h(a1 * inv);
    r.z = f2h(a2 * inv); r.w = f2h(a3 * inv);
    *(us4*)(y + (size_t)bn * O_ + og * 4) = r;
}

// ---------------------------------------------------------------------------
// Kernel 3: z[b][c][n] = sum_o wW[c][o] y[b][n][o] + bW[c] + x[b][c][n]
// ---------------------------------------------------------------------------
__global__ __launch_bounds__(256) void out_kernel(
    const unsigned short* __restrict__ y,
    const void* __restrict__ wW,
    const void* __restrict__ bW,
    const void* __restrict__ x,
    const int*  __restrict__ flag,
    void* __restrict__ z)
{
    const int isf32 = *flag;
    const int b  = blockIdx.z;
    const int c0 = blockIdx.y * 64;
    const int n0 = blockIdx.x * 128;
    const int tid  = threadIdx.x;
    const int wv   = tid >> 6, lane = tid & 63;
    const int quad = lane >> 4, l16 = lane & 15;

    __shared__ alignas(16) unsigned short Ys[128][136];
    __shared__ alignas(16) unsigned short Ws[64][136];

    for (int it = 0; it < 16; it++) {
        int l = it * 256 + tid;
        int nn = l >> 5;
        int og = l & 31;
        us4 v = *(const us4*)(y + (size_t)(b * N_ + n0 + nn) * O_ + og * 4);
        *(us4*)&Ys[nn][og * 4] = v;
    }
    for (int it = 0; it < 8; it++) {
        int l = it * 256 + tid;
        int cc = l >> 5;
        int og = l & 31;
        float v[4];
        load4f(wW, (size_t)(c0 + cc) * O_ + og * 4, isf32, v);
        Ws[cc][og * 4 + 0] = f2h(v[0]);
        Ws[cc][og * 4 + 1] = f2h(v[1]);
        Ws[cc][og * 4 + 2] = f2h(v[2]);
        Ws[cc][og * 4 + 3] = f2h(v[3]);
    }
    __syncthreads();

    f32x4 acc[8];
    for (int i = 0; i < 8; i++) acc[i] = (f32x4)0.f;
    for (int s = 0; s < 4; s++) {
        f16x8 a = *(const f16x8*)&Ws[wv * 16 + l16][s * 32 + quad * 8];
        for (int nt = 0; nt < 8; nt++) {
            f16x8 bb = *(const f16x8*)&Ys[nt * 16 + l16][s * 32 + quad * 8];
            acc[nt] = __builtin_amdgcn_mfma_f32_16x16x32_f16(a, bb, acc[nt], 0, 0, 0);
        }
    }
    for (int r = 0; r < 4; r++) {
        int c = c0 + wv * 16 + quad * 4 + r;
        float bias = load1f(bW, c, isf32);
        for (int nt = 0; nt < 8; nt++) {
            int n = n0 + nt * 16 + l16;
            size_t idx = (size_t)(b * C_ + c) * N_ + n;
            float zv = acc[nt][r] + bias + load1f(x, idx, isf32);
            if (isf32) ((float*)z)[idx] = zv;
            else       ((unsigned short*)z)[idx] = f2bf(zv);
        }
    }
}

// ---------------------------------------------------------------------------
extern "C" void kernel_launch(void* const* d_in, const int* in_sizes, int n_in,
                              void* d_out, int out_size, void* d_ws, size_t ws_size,
                              hipStream_t stream) {
    const void* x  = d_in[0];
    const void* wt = d_in[1];
    const void* bt = d_in[2];
    const void* wp = d_in[3];
    const void* bp = d_in[4];
    const void* wg = d_in[5];
    const void* bg = d_in[6];
    const void* wW = d_in[7];
    const void* bW = d_in[8];

    // split factor from ws_size (constant across calls -> graph-safe)
    const size_t base = 64 + 8388608 /*thph*/ + 4194304 /*gT*/;
    const size_t per_split = 4194304 /*partO*/ + 131072 /*pm+pl*/;
    int S = 4;   // 512 blocks -> 2 blocks/CU
    while (S > 1 && base + (size_t)S * per_split > ws_size) S--;

    char* p = (char*)d_ws;
    int* flag = (int*)p;                    p += 64;
    unsigned short* thph = (unsigned short*)p;  p += 8388608;
    unsigned short* gT   = (unsigned short*)p;  p += 4194304;
    unsigned short* partO = (unsigned short*)p; p += (size_t)S * 4194304;
    float* pm = (float*)p;                  p += (size_t)S * 65536;
    float* pl = (float*)p;
    unsigned short* y = gT;   // gT dead after attn_partial; reuse for y

    detect_kernel<<<1, 256, 0, stream>>>((const unsigned short*)x, flag);

    dim3 g1(N_ / 64, 3, B_);
    qkv_kernel<<<g1, 256, 0, stream>>>(x, wt, wp, wg, bt, bp, bg, flag, thph, gT);

    dim3 g2(N_ / 128, S, B_);
    attn_partial<<<g2, 256, 0, stream>>>(thph, gT, partO, pm, pl, S);

    merge_kernel<<<(B_ * N_ * 32) / 256, 256, 0, stream>>>(partO, pm, pl, y, S);

    dim3 g3(N_ / 128, C_ / 64, B_);
    out_kernel<<<g3, 256, 0, stream>>>(y, wW, bW, x, flag, d_out);
}